// Round 11
// baseline (287.220 us; speedup 1.0000x reference)
//
#include <hip/hip_runtime.h>
#include <math.h>

// ---------------- problem constants ----------------
#define D    128
#define PN   2048
#define MN   100000
#define KK   50
#define NEGF (-3.0e38f)
#define TPW  49                   // 16-col tiles per col-worker
#define CPW  784                  // cols per worker: TPW*16
#define NCP  128                  // col partitions (workers)
#define SCAP 16                   // per-(row,worker) strip cap

typedef __attribute__((ext_vector_type(8))) short short8;
typedef __attribute__((ext_vector_type(4))) float f32x4;

__device__ __forceinline__ bool pgtf(float va, int ia, float vb, int ib) {
  return (va > vb) || (va == vb && ia < ib);
}

__device__ __forceinline__ unsigned short f2bf(float x) {
  union { float f; unsigned u; } c; c.f = x;
  unsigned r = c.u + 0x7FFFu + ((c.u >> 16) & 1u);   // round-to-nearest-even
  return (unsigned short)(r >> 16);
}

// ---------------- kernel 1: FULLY FUSED prep+screen (2-dispatch pipeline) ----
// Per block (512 blocks, 256 thr, 2 blocks/CU):
//  (a) logits side-job: verbatim fp64 chain for patches blockIdx*4+wv
//  (b) A-panel: bf16(X*rinv) computed in-register — identical expression order
//      to the old cvtA (per-ks 8-elem sumsq, shfl_xor(16)/(32) hi-reduce,
//      tot = ((ss0+ss1)+ss2)+ss3, rinv = 1/(3*sqrt(tot)), f2bf) -> bit-identical
//  (c) screen: identical MFMA loop; B loaded as fp32 from Bn and converted
//      in-register with the same f2bf (elementwise -> identical bf16 values)
__global__ __launch_bounds__(256, 2)
void k_sim(const float* __restrict__ X, const float* __restrict__ Bn,
           const float* __restrict__ W1, const float* __restrict__ b1,
           const float* __restrict__ W2, const float* __restrict__ b2,
           unsigned short* __restrict__ cand2, unsigned char* __restrict__ cnt2,
           float* __restrict__ logits) {
  __shared__ int lcnt[4][128];

  const int tid  = threadIdx.x;
  const int lane = tid & 63;
  const int wv   = __builtin_amdgcn_readfirstlane(tid >> 6);
  const int xq = blockIdx.x & 7, kq = blockIdx.x >> 3;
  const int w  = xq * 16 + (kq & 15);   // col-worker 0..127 (stripe of 784 cols)
  const int g  = kq >> 4;               // row-block group 0..3
  const int rb = g * 4 + wv;            // this wave's row-block 0..15
  const int row0 = rb * 128;

  // ---- (a) logits side-job: verbatim value-system ----
  {
    int p = blockIdx.x * 4 + wv;        // 512 blocks x 4 waves = 2048 patches
    const float* xp = X + (size_t)p * D;
    double h = (double)b1[lane];
#pragma unroll 4
    for (int k = 0; k < D; ++k) h += (double)xp[k] * (double)W1[k * 64 + lane];
    float hf = fmaxf((float)h, 0.f);
    double y = (double)hf * (double)W2[lane];
#pragma unroll
    for (int s = 32; s > 0; s >>= 1) y += __shfl_xor(y, s, 64);
    if (lane == 0) logits[p] = (float)(y + (double)b2[0]);
  }

  lcnt[wv][lane] = 0; lcnt[wv][lane + 64] = 0;
  __syncthreads();

  const int coll = lane & 15;
  const int hi   = lane >> 4;           // 0..3
  const int rql  = hi * 4;

  // ---- (b) A panel: 128 rows x 128 K bf16, computed from X in-register ----
  short8 a[8][4];
#pragma unroll
  for (int rt = 0; rt < 8; ++rt) {
    int row = row0 + rt * 16 + coll;
    const float4* sp = (const float4*)(X + (size_t)row * D + hi * 8);
    float4 f0[4], f1[4];
#pragma unroll
    for (int ks = 0; ks < 4; ++ks) { f0[ks] = sp[ks * 8]; f1[ks] = sp[ks * 8 + 1]; }
    float ssk[4];
#pragma unroll
    for (int ks = 0; ks < 4; ++ks) {
      float ss = f0[ks].x*f0[ks].x + f0[ks].y*f0[ks].y + f0[ks].z*f0[ks].z + f0[ks].w*f0[ks].w
               + f1[ks].x*f1[ks].x + f1[ks].y*f1[ks].y + f1[ks].z*f1[ks].z + f1[ks].w*f1[ks].w;
      ss += __shfl_xor(ss, 16, 64);     // reduce over hi (same order as cvtA)
      ss += __shfl_xor(ss, 32, 64);
      ssk[ks] = ss;
    }
    float tot  = ssk[0] + ssk[1] + ssk[2] + ssk[3];   // same association as cvtA
    float rinv = 1.0f / (3.0f * sqrtf(tot));
#pragma unroll
    for (int ks = 0; ks < 4; ++ks) {
      short8 h;
      h[0]=(short)f2bf(f0[ks].x*rinv); h[1]=(short)f2bf(f0[ks].y*rinv);
      h[2]=(short)f2bf(f0[ks].z*rinv); h[3]=(short)f2bf(f0[ks].w*rinv);
      h[4]=(short)f2bf(f1[ks].x*rinv); h[5]=(short)f2bf(f1[ks].y*rinv);
      h[6]=(short)f2bf(f1[ks].z*rinv); h[7]=(short)f2bf(f1[ks].w*rinv);
      a[rt][ks] = h;
    }
  }

  // ---- (c) screen: identical MFMA loop; B from Bn fp32 + in-register f2bf ----
  const int wbase = w * TPW;            // first 16-col tile of this stripe
  const f32x4 cinit = {-1.f, -1.f, -1.f, -1.f};

  auto loadRaw = [&](float4* r, int s) {
    int n = (wbase + s) * 16 + coll;    // global column for this lane
    if (n < MN) {
      const float4* bp = (const float4*)(Bn + (size_t)n * D + hi * 8);
#pragma unroll
      for (int ks = 0; ks < 4; ++ks) { r[ks * 2] = bp[ks * 8]; r[ks * 2 + 1] = bp[ks * 8 + 1]; }
    } else {
      float4 z = {0.f, 0.f, 0.f, 0.f};
#pragma unroll
      for (int j = 0; j < 8; ++j) r[j] = z;
    }
  };
  auto cvtTo = [&](short8* dst, const float4* r) {
#pragma unroll
    for (int ks = 0; ks < 4; ++ks) {
      float4 q0 = r[ks * 2], q1 = r[ks * 2 + 1];
      short8 h;
      h[0]=(short)f2bf(q0.x); h[1]=(short)f2bf(q0.y); h[2]=(short)f2bf(q0.z); h[3]=(short)f2bf(q0.w);
      h[4]=(short)f2bf(q1.x); h[5]=(short)f2bf(q1.y); h[6]=(short)f2bf(q1.z); h[7]=(short)f2bf(q1.w);
      dst[ks] = h;
    }
  };

  auto step = [&](const short8* bf, int s) {
    f32x4 acc[8];
#pragma unroll
    for (int rt = 0; rt < 8; ++rt)
      acc[rt] = __builtin_amdgcn_mfma_f32_16x16x32_bf16(a[rt][0], bf[0], cinit, 0, 0, 0);
#pragma unroll
    for (int ks = 1; ks < 4; ++ks)
#pragma unroll
      for (int rt = 0; rt < 8; ++rt)
        acc[rt] = __builtin_amdgcn_mfma_f32_16x16x32_bf16(a[rt][ks], bf[ks], acc[rt], 0, 0, 0);

    unsigned miss = 0;
#pragma unroll
    for (int rt = 0; rt < 8; ++rt)
#pragma unroll
      for (int rg = 0; rg < 4; ++rg)
        miss |= (__float_as_uint(acc[rt][rg]) >> 31) << (unsigned)(rt * 4 + rg);
    unsigned m0 = ~miss;
    if (m0) {
      int gc = (wbase + s) * 16 + coll;   // global column of this lane
      unsigned short code = (unsigned short)(s * 16 + coll);
#pragma unroll 1
      while (m0) {
        int b2i = __builtin_ctz(m0); m0 &= m0 - 1;
        int rt = b2i >> 2, rg = b2i & 3;
        if (gc < MN) {
          int row_l = rt * 16 + rql + rg;
          int pos = atomicAdd(&lcnt[wv][row_l], 1);
          if (pos < SCAP) {
            size_t strip = (size_t)(row0 + row_l) * NCP + w;
            cand2[strip * SCAP + pos] = code;
          }
        }
      }
    }
  };

  float4 r[8];
  short8 cur[4];
  loadRaw(r, 0);
  cvtTo(cur, r);
#pragma unroll 1
  for (int s = 0; s < TPW; ++s) {
    if (s + 1 < TPW) loadRaw(r, s + 1);   // issue next-tile loads (hidden by MFMA)
    step(cur, s);
    if (s + 1 < TPW) cvtTo(cur, r);       // loads complete under step; convert
  }

  __syncthreads();
#pragma unroll
  for (int rr = 0; rr < 2; ++rr) {
    int rx = rr * 64 + lane;
    int cc = lcnt[wv][rx]; if (cc > SCAP) cc = SCAP;
    cnt2[(size_t)(row0 + rx) * NCP + w] = (unsigned char)cc;
  }
}

// ---------------- kernel 2: R2-verbatim. block 0 = pool; blocks 1..PN = compact +
//   FROZEN even/odd fp32 chain rescore + LDS bitonic-512 + top-50 ----
__global__ __launch_bounds__(512)
void k_select(const unsigned short* __restrict__ cand2, const unsigned char* __restrict__ cnt2,
              const float* __restrict__ A, const float* __restrict__ Bn,
              const float* __restrict__ logits, float* __restrict__ out) {
  __shared__ float Ash[D];
  __shared__ int   ixsh[512];
  __shared__ float svsh[512];
  __shared__ int   nsh;
  __shared__ float  wsum2[2048];    // pool path
  __shared__ double redp[512];
  __shared__ double gpart[128];

  const int tid  = threadIdx.x;
  const int lane = tid & 63;

  if (blockIdx.x == 0) {
    // ================= pool (512 threads; fp64 reassociation only) =================
    float lv[4];
    float mx = NEGF;
#pragma unroll
    for (int j = 0; j < 4; ++j) { lv[j] = logits[j * 512 + tid]; mx = fmaxf(mx, lv[j]); }
    redp[tid] = (double)mx;
    __syncthreads();
    for (int s = 256; s > 0; s >>= 1) { if (tid < s) redp[tid] = fmax(redp[tid], redp[tid + s]); __syncthreads(); }
    float m = (float)redp[0];
    __syncthreads();
    double ssum = 0.0;
#pragma unroll
    for (int j = 0; j < 4; ++j) {
      float e = expf(lv[j] - m);
      wsum2[j * 512 + tid] = e;
      ssum += (double)e;
    }
    redp[tid] = ssum;
    __syncthreads();
    for (int s = 256; s > 0; s >>= 1) { if (tid < s) redp[tid] += redp[tid + s]; __syncthreads(); }
    double S = redp[0];
    __syncthreads();
    int dim = tid & 127, q = tid >> 7;  // q = 0..3, 512 patches each
    const float* xq = A + (size_t)(q * 512) * D + dim;
    double acc = 0.0;
#pragma unroll 4
    for (int p = 0; p < 512; ++p) acc += (double)wsum2[q * 512 + p] * (double)xq[(size_t)p * D];
    redp[tid] = acc;
    __syncthreads();
    if (tid < 128) {
      double g = (redp[tid] + redp[tid + 128] + redp[tid + 256] + redp[tid + 384]) / S;
      gpart[tid] = g;
      redp[tid] = g * g;
    }
    __syncthreads();
    for (int s = 64; s > 0; s >>= 1) { if (tid < s) redp[tid] += redp[tid + s]; __syncthreads(); }
    if (tid < 128) {
      double nrm = sqrt(redp[0]);
      out[(size_t)2 * PN * KK + tid] = (float)(gpart[tid] / fmax(nrm, 1e-12));
    }
    return;
  }

  // ================= top-50 select =================
  const int row = blockIdx.x - 1;

  if (tid < D / 4) ((float4*)Ash)[tid] = ((const float4*)(A + (size_t)row * D))[tid];

  if (tid < 64) {
    // wave 0: compact 128 strips via prefix scan (order-independent set)
    size_t s0 = (size_t)row * NCP + lane;
    size_t s1 = s0 + 64;
    int c0 = cnt2[s0], c1 = cnt2[s1];
    int x = c0 + c1, incl = x;
#pragma unroll
    for (int d2 = 1; d2 < 64; d2 <<= 1) {
      int y = __shfl_up(incl, d2, 64);
      if (lane >= d2) incl += y;
    }
    int off = incl - x;
    int n = __shfl(incl, 63, 64);
    if (n > 512) n = 512;
#pragma unroll 1
    for (int q = 0; q < c0; ++q) {
      int code = cand2[s0 * SCAP + q];
      int pos = off + q;
      if (pos < 512) ixsh[pos] = lane * CPW + code;
    }
#pragma unroll 1
    for (int q = 0; q < c1; ++q) {
      int code = cand2[s1 * SCAP + q];
      int pos = off + c0 + q;
      if (pos < 512) ixsh[pos] = (lane + 64) * CPW + code;
    }
    if (lane == 0) nsh = n;
  }
  __syncthreads();
  const int n = nsh;

  // score: 512 threads, one candidate each — frozen even/odd split fused fp32 chains
  if (tid < n) {
    int gc = ixsh[tid];
    const float4* Br = (const float4*)(Bn + (size_t)gc * D);
    float ae = 0.f, ao = 0.f;
#pragma unroll 2
    for (int kb = 0; kb < 8; ++kb) {
      float4 b0 = Br[kb * 4 + 0];
      float4 b1 = Br[kb * 4 + 1];
      float4 b2 = Br[kb * 4 + 2];
      float4 b3 = Br[kb * 4 + 3];
      const float* Ak = Ash + kb * 16;
      ae = __builtin_fmaf(Ak[0],  b0.x, ae); ao = __builtin_fmaf(Ak[1],  b0.y, ao);
      ae = __builtin_fmaf(Ak[2],  b0.z, ae); ao = __builtin_fmaf(Ak[3],  b0.w, ao);
      ae = __builtin_fmaf(Ak[4],  b1.x, ae); ao = __builtin_fmaf(Ak[5],  b1.y, ao);
      ae = __builtin_fmaf(Ak[6],  b1.z, ae); ao = __builtin_fmaf(Ak[7],  b1.w, ao);
      ae = __builtin_fmaf(Ak[8],  b2.x, ae); ao = __builtin_fmaf(Ak[9],  b2.y, ao);
      ae = __builtin_fmaf(Ak[10], b2.z, ae); ao = __builtin_fmaf(Ak[11], b2.w, ao);
      ae = __builtin_fmaf(Ak[12], b3.x, ae); ao = __builtin_fmaf(Ak[13], b3.y, ao);
      ae = __builtin_fmaf(Ak[14], b3.z, ae); ao = __builtin_fmaf(Ak[15], b3.w, ao);
    }
    svsh[tid] = ae + ao;
  } else {
    svsh[tid] = NEGF;
    ixsh[tid] = 0x40000000 + tid;   // unique pads -> strict total order
  }
  __syncthreads();

  // bitonic-512, descending, (value, idx-asc) comparator — 256 compare threads
#pragma unroll 1
  for (int size = 2; size <= 512; size <<= 1) {
#pragma unroll 1
    for (int stride = size >> 1; stride > 0; stride >>= 1) {
      if (tid < 256) {
        int l = ((tid & ~(stride - 1)) << 1) | (tid & (stride - 1));
        int m = l | stride;
        bool desc = ((l & size) == 0);
        float vl = svsh[l], vm = svsh[m];
        int   il = ixsh[l], im = ixsh[m];
        bool g = pgtf(vm, im, vl, il);
        if (g == desc) {
          svsh[l] = vm; svsh[m] = vl;
          ixsh[l] = im; ixsh[m] = il;
        }
      }
      __syncthreads();
    }
  }

  if (tid < KK) {
    out[(size_t)row * KK + tid] = (float)ixsh[tid];
    out[(size_t)(PN * KK) + (size_t)row * KK + tid] = (float)row;
  }
}

// ---------------- launcher: 2 dispatches ----------------
extern "C" void kernel_launch(void* const* d_in, const int* in_sizes, int n_in,
                              void* d_out, int out_size, void* d_ws, size_t ws_size,
                              hipStream_t stream) {
  const float* X  = (const float*)d_in[0];   // [2048,128]
  const float* Bn = (const float*)d_in[1];   // [100000,128]
  const float* W1 = (const float*)d_in[2];   // [128,64]
  const float* b1 = (const float*)d_in[3];   // [64]
  const float* W2 = (const float*)d_in[4];   // [64,1]
  const float* b2 = (const float*)d_in[5];   // [1]
  float* out = (float*)d_out;                // 2*2048*50 edge floats + 128 g floats

  char* p = (char*)d_ws;
  unsigned short* cand2 = (unsigned short*)p; p += (size_t)PN * NCP * SCAP * 2;  // 8.4 MB
  unsigned char*  cnt2  = (unsigned char*)p;  p += (size_t)PN * NCP;             // 0.26 MB
  float* logits = (float*)p;                  p += (size_t)PN * 4;

  k_sim<<<512, 256, 0, stream>>>(X, Bn, W1, b1, W2, b2, cand2, cnt2, logits);
  k_select<<<PN + 1, 512, 0, stream>>>(cand2, cnt2, X, Bn, logits, out);
}

// Round 12
// 198.473 us; speedup vs baseline: 1.4472x; 1.4472x over previous
//
#include <hip/hip_runtime.h>
#include <math.h>

// ---------------- problem constants ----------------
#define D    128
#define PN   2048
#define MN   100000
#define KK   50
#define NEGF (-3.0e38f)
#define NCB  784                  // 128-col chunks incl. zero-pad: 784*128 = 100352
#define NTILE 6272                // 16-col tiles: NCB*8
#define TPW  49                   // tiles per col-worker: 6272/128
#define CPW  784                  // cols per worker: TPW*16
#define NRB  16                   // row blocks: 2048/128
#define NCP  128                  // col partitions (workers)
#define SCAP 16                   // per-(row,worker) strip cap
// k_prep grid segments
#define PB_CVTB 6272              // NCB*8 blocks
#define PB_CVTA (PB_CVTB + 128)
#define PB_ALL  (PB_CVTA + 512)

typedef __attribute__((ext_vector_type(8))) short short8;
typedef __attribute__((ext_vector_type(4))) float f32x4;

__device__ __forceinline__ bool pgtf(float va, int ia, float vb, int ib) {
  return (va > vb) || (va == vb && ia < ib);
}

__device__ __forceinline__ unsigned short f2bf(float x) {
  union { float f; unsigned u; } c; c.f = x;
  unsigned r = c.u + 0x7FFFu + ((c.u >> 16) & 1u);   // round-to-nearest-even
  return (unsigned short)(r >> 16);
}

// ---------------- kernel 0: fused prep (cvtB | cvtA(scaled by 1/tau) | logits) ----
__global__ __launch_bounds__(256)
void k_prep(const float* __restrict__ X, const float* __restrict__ Bn,
            const float* __restrict__ W1, const float* __restrict__ b1,
            const float* __restrict__ W2, const float* __restrict__ b2,
            short* __restrict__ Ap, short* __restrict__ Bp,
            float* __restrict__ logits) {
  __shared__ float part[4][16];
  const int b   = blockIdx.x;
  const int tid = threadIdx.x;

  if (b < PB_CVTB) {
    int q = b * 256 + tid;
    int cb = q >> 11, t = q & 2047;
    int ct = t >> 8, ks = (t >> 6) & 3, l = t & 63;
    int n  = cb * 128 + ct * 16 + (l & 15);
    int k0 = ks * 32 + (l >> 4) * 8;
    short8 h = {0, 0, 0, 0, 0, 0, 0, 0};
    if (n < MN) {
      const float4* s = (const float4*)(Bn + (size_t)n * D + k0);
      float4 f0 = s[0], f1 = s[1];
      h[0]=(short)f2bf(f0.x); h[1]=(short)f2bf(f0.y); h[2]=(short)f2bf(f0.z); h[3]=(short)f2bf(f0.w);
      h[4]=(short)f2bf(f1.x); h[5]=(short)f2bf(f1.y); h[6]=(short)f2bf(f1.z); h[7]=(short)f2bf(f1.w);
    }
    *(short8*)(Bp + (size_t)q * 8) = h;
  } else if (b < PB_CVTA) {
    int bb = b - PB_CVTB;            // 0..127; block owns rows rb*128 + rt*16 + [0,16)
    int rb = bb >> 3, rt = bb & 7;
    int ks = tid >> 6, hi = (tid >> 4) & 3, rsel = tid & 15;
    int m  = rb * 128 + rt * 16 + rsel;
    int k0 = ks * 32 + hi * 8;
    const float4* sp = (const float4*)(X + (size_t)m * D + k0);
    float4 f0 = sp[0], f1 = sp[1];
    float ss = f0.x*f0.x + f0.y*f0.y + f0.z*f0.z + f0.w*f0.w
             + f1.x*f1.x + f1.y*f1.y + f1.z*f1.z + f1.w*f1.w;
    ss += __shfl_xor(ss, 16, 64);    // reduce over hi within wave
    ss += __shfl_xor(ss, 32, 64);
    if ((tid & 63) < 16) part[ks][rsel] = ss;
    __syncthreads();
    float tot = part[0][rsel] + part[1][rsel] + part[2][rsel] + part[3][rsel];
    float rinv = 1.0f / (3.0f * sqrtf(tot));
    short8 h;
    h[0]=(short)f2bf(f0.x*rinv); h[1]=(short)f2bf(f0.y*rinv);
    h[2]=(short)f2bf(f0.z*rinv); h[3]=(short)f2bf(f0.w*rinv);
    h[4]=(short)f2bf(f1.x*rinv); h[5]=(short)f2bf(f1.y*rinv);
    h[6]=(short)f2bf(f1.z*rinv); h[7]=(short)f2bf(f1.w*rinv);
    *(short8*)(Ap + (size_t)(bb * 256 + tid) * 8) = h;
  } else {
    int w = tid >> 6, lane = tid & 63;
    int p = (b - PB_CVTA) * 4 + w;
    const float* xp = X + (size_t)p * D;
    double h = (double)b1[lane];
#pragma unroll 4
    for (int k = 0; k < D; ++k) h += (double)xp[k] * (double)W1[k * 64 + lane];
    float hf = fmaxf((float)h, 0.f);
    double y = (double)hf * (double)W2[lane];
#pragma unroll
    for (int s = 32; s > 0; s >>= 1) y += __shfl_xor(y, s, 64);
    if (lane == 0) logits[p] = (float)(y + (double)b2[0]);
  }
}

// ---------------- kernel 1: LDS-free column-split bf16 MFMA screen ----------------
__global__ __launch_bounds__(256, 2)
void k_sim(const short* __restrict__ Ap, const short* __restrict__ Bp,
           unsigned short* __restrict__ cand2, unsigned char* __restrict__ cnt2) {
  __shared__ int lcnt[4][128];

  const int tid  = threadIdx.x;
  const int lane = tid & 63;
  const int wv   = __builtin_amdgcn_readfirstlane(tid >> 6);
  const int xq = blockIdx.x & 7, kq = blockIdx.x >> 3;
  const int w  = xq * 16 + (kq & 15);   // col-worker 0..127 (stripe of 784 cols)
  const int g  = kq >> 4;               // row-block group 0..3
  const int rb = g * 4 + wv;            // this wave's row-block 0..15
  const int row0 = rb * 128;

  lcnt[wv][lane] = 0; lcnt[wv][lane + 64] = 0;
  __syncthreads();

  const int coll = lane & 15;
  const int rql  = (lane >> 4) * 4;

  // A panel: 128 rows x 128 K, bf16, 32 short8 = 128 VGPR
  short8 a[8][4];
  const short8* gA = (const short8*)(Ap + (size_t)rb * 16384);
#pragma unroll
  for (int rt = 0; rt < 8; ++rt)
#pragma unroll
    for (int ks = 0; ks < 4; ++ks)
      a[rt][ks] = gA[(rt * 4 + ks) * 64 + lane];

  const int wbase = w * TPW;            // first 16-col tile of this stripe
  const f32x4 cinit = {-1.f, -1.f, -1.f, -1.f};

  auto loadB = [&](short8* dst, int s) {
    const short8* gB = (const short8*)Bp + (size_t)(wbase + s) * 256 + lane;
#pragma unroll
    for (int ks = 0; ks < 4; ++ks) dst[ks] = gB[ks * 64];
  };

  auto step = [&](const short8* bf, int s) {
    f32x4 acc[8];
#pragma unroll
    for (int rt = 0; rt < 8; ++rt)
      acc[rt] = __builtin_amdgcn_mfma_f32_16x16x32_bf16(a[rt][0], bf[0], cinit, 0, 0, 0);
#pragma unroll
    for (int ks = 1; ks < 4; ++ks)
#pragma unroll
      for (int rt = 0; rt < 8; ++rt)
        acc[rt] = __builtin_amdgcn_mfma_f32_16x16x32_bf16(a[rt][ks], bf[ks], acc[rt], 0, 0, 0);

    unsigned miss = 0;
#pragma unroll
    for (int rt = 0; rt < 8; ++rt)
#pragma unroll
      for (int rg = 0; rg < 4; ++rg)
        miss |= (__float_as_uint(acc[rt][rg]) >> 31) << (unsigned)(rt * 4 + rg);
    unsigned m0 = ~miss;
    if (m0) {
      int gc = (wbase + s) * 16 + coll;   // global column of this lane
      unsigned short code = (unsigned short)(s * 16 + coll);
#pragma unroll 1
      while (m0) {
        int b2 = __builtin_ctz(m0); m0 &= m0 - 1;
        int rt = b2 >> 2, rg = b2 & 3;
        if (gc < MN) {
          int row_l = rt * 16 + rql + rg;
          int pos = atomicAdd(&lcnt[wv][row_l], 1);
          if (pos < SCAP) {
            size_t strip = (size_t)(row0 + row_l) * NCP + w;
            cand2[strip * SCAP + pos] = code;
          }
        }
      }
    }
  };

  short8 u[4], v[4];
  loadB(u, 0);
#pragma unroll 1
  for (int s = 0; s < TPW - 1; s += 2) {   // s = 0,2,...,46
    loadB(v, s + 1);
    step(u, s);
    loadB(u, s + 2);                        // s+2 <= 48, always valid
    step(v, s + 1);
  }
  step(u, TPW - 1);

  __syncthreads();
#pragma unroll
  for (int rr = 0; rr < 2; ++rr) {
    int r = rr * 64 + lane;
    int cc = lcnt[wv][r]; if (cc > SCAP) cc = SCAP;
    cnt2[(size_t)(row0 + r) * NCP + w] = (unsigned char)cc;
  }
}

// ---------------- kernel 2: block 0 = pool; blocks 1..PN:
//   compact + FROZEN rescore (one cand/thread, full TLP) + hybrid bitonic-512:
//   stride<64 -> shfl_xor in registers (no barriers), stride>=64 -> 6 LDS stages. ----
__global__ __launch_bounds__(512)
void k_select(const unsigned short* __restrict__ cand2, const unsigned char* __restrict__ cnt2,
              const float* __restrict__ A, const float* __restrict__ Bn,
              const float* __restrict__ logits, float* __restrict__ out) {
  __shared__ float Ash[D];
  __shared__ int   ixsh[512];
  __shared__ float svsh[512];
  __shared__ int   nsh;
  __shared__ float  wsum2[2048];    // pool path
  __shared__ double redp[512];
  __shared__ double gpart[128];

  const int tid  = threadIdx.x;
  const int lane = tid & 63;

  if (blockIdx.x == 0) {
    // ================= pool (512 threads; fp64 reassociation only) =================
    float lv[4];
    float mx = NEGF;
#pragma unroll
    for (int j = 0; j < 4; ++j) { lv[j] = logits[j * 512 + tid]; mx = fmaxf(mx, lv[j]); }
    redp[tid] = (double)mx;
    __syncthreads();
    for (int s = 256; s > 0; s >>= 1) { if (tid < s) redp[tid] = fmax(redp[tid], redp[tid + s]); __syncthreads(); }
    float m = (float)redp[0];
    __syncthreads();
    double ssum = 0.0;
#pragma unroll
    for (int j = 0; j < 4; ++j) {
      float e = expf(lv[j] - m);
      wsum2[j * 512 + tid] = e;
      ssum += (double)e;
    }
    redp[tid] = ssum;
    __syncthreads();
    for (int s = 256; s > 0; s >>= 1) { if (tid < s) redp[tid] += redp[tid + s]; __syncthreads(); }
    double S = redp[0];
    __syncthreads();
    int dim = tid & 127, q = tid >> 7;  // q = 0..3, 512 patches each
    const float* xq = A + (size_t)(q * 512) * D + dim;
    double acc = 0.0;
#pragma unroll 4
    for (int p = 0; p < 512; ++p) acc += (double)wsum2[q * 512 + p] * (double)xq[(size_t)p * D];
    redp[tid] = acc;
    __syncthreads();
    if (tid < 128) {
      double g = (redp[tid] + redp[tid + 128] + redp[tid + 256] + redp[tid + 384]) / S;
      gpart[tid] = g;
      redp[tid] = g * g;
    }
    __syncthreads();
    for (int s = 64; s > 0; s >>= 1) { if (tid < s) redp[tid] += redp[tid + s]; __syncthreads(); }
    if (tid < 128) {
      double nrm = sqrt(redp[0]);
      out[(size_t)2 * PN * KK + tid] = (float)(gpart[tid] / fmax(nrm, 1e-12));
    }
    return;
  }

  // ================= top-50 select =================
  const int row = blockIdx.x - 1;

  if (tid < D / 4) ((float4*)Ash)[tid] = ((const float4*)(A + (size_t)row * D))[tid];

  if (tid < 64) {
    // wave 0: compact 128 strips via prefix scan (order-independent set)
    size_t s0 = (size_t)row * NCP + lane;
    size_t s1 = s0 + 64;
    int c0 = cnt2[s0], c1 = cnt2[s1];
    int x = c0 + c1, incl = x;
#pragma unroll
    for (int d2 = 1; d2 < 64; d2 <<= 1) {
      int y = __shfl_up(incl, d2, 64);
      if (lane >= d2) incl += y;
    }
    int off = incl - x;
    int n = __shfl(incl, 63, 64);
    if (n > 512) n = 512;
#pragma unroll 1
    for (int q = 0; q < c0; ++q) {
      int pos = off + q;
      if (pos < 512) ixsh[pos] = lane * CPW + cand2[s0 * SCAP + q];
    }
#pragma unroll 1
    for (int q = 0; q < c1; ++q) {
      int pos = off + c0 + q;
      if (pos < 512) ixsh[pos] = (lane + 64) * CPW + cand2[s1 * SCAP + q];
    }
    if (lane == 0) nsh = n;
  }
  __syncthreads();
  const int n = nsh;

  // score: 512 threads, one candidate each — frozen even/odd split fused fp32 chains
  float v; int i;
  if (tid < n) {
    i = ixsh[tid];
    const float4* Br = (const float4*)(Bn + (size_t)i * D);
    float ae = 0.f, ao = 0.f;
#pragma unroll 2
    for (int kb = 0; kb < 8; ++kb) {
      float4 b0 = Br[kb * 4 + 0];
      float4 b1 = Br[kb * 4 + 1];
      float4 b2 = Br[kb * 4 + 2];
      float4 b3 = Br[kb * 4 + 3];
      const float* Ak = Ash + kb * 16;
      ae = __builtin_fmaf(Ak[0],  b0.x, ae); ao = __builtin_fmaf(Ak[1],  b0.y, ao);
      ae = __builtin_fmaf(Ak[2],  b0.z, ae); ao = __builtin_fmaf(Ak[3],  b0.w, ao);
      ae = __builtin_fmaf(Ak[4],  b1.x, ae); ao = __builtin_fmaf(Ak[5],  b1.y, ao);
      ae = __builtin_fmaf(Ak[6],  b1.z, ae); ao = __builtin_fmaf(Ak[7],  b1.w, ao);
      ae = __builtin_fmaf(Ak[8],  b2.x, ae); ao = __builtin_fmaf(Ak[9],  b2.y, ao);
      ae = __builtin_fmaf(Ak[10], b2.z, ae); ao = __builtin_fmaf(Ak[11], b2.w, ao);
      ae = __builtin_fmaf(Ak[12], b3.x, ae); ao = __builtin_fmaf(Ak[13], b3.y, ao);
      ae = __builtin_fmaf(Ak[14], b3.z, ae); ao = __builtin_fmaf(Ak[15], b3.w, ao);
    }
    v = ae + ao;
  } else {
    v = NEGF;
    i = 0x40000000 + tid;   // unique pads -> strict total order
  }

  // hybrid bitonic-512, descending, (value, idx-asc) comparator; element e = tid.
  // desc = ((tid & size)==0) is valid for both partners since stride < size.
#pragma unroll
  for (int size = 2; size <= 512; size <<= 1) {
#pragma unroll
    for (int stride = size >> 1; stride > 0; stride >>= 1) {
      const bool desc = ((tid & size) == 0);
      if (stride >= 64) {
        __syncthreads();               // prior reads of svsh/ixsh (or scoring) done
        svsh[tid] = v; ixsh[tid] = i;
        __syncthreads();
        int p = tid ^ stride;
        float pv = svsh[p]; int pi = ixsh[p];
        bool lower = (tid & stride) == 0;
        bool g = lower ? pgtf(pv, pi, v, i) : pgtf(v, i, pv, pi);
        if (g == desc) { v = pv; i = pi; }
      } else {
        float pv = __shfl_xor(v, stride, 64);
        int   pi = __shfl_xor(i, stride, 64);
        bool lower = (lane & stride) == 0;
        bool g = lower ? pgtf(pv, pi, v, i) : pgtf(v, i, pv, pi);
        if (g == desc) { v = pv; i = pi; }
      }
    }
  }

  // element e = tid holds sorted rank tid
  if (tid < KK) {
    out[(size_t)row * KK + tid] = (float)i;
    out[(size_t)(PN * KK) + (size_t)row * KK + tid] = (float)row;
  }
}

// ---------------- launcher: 3 dispatches ----------------
extern "C" void kernel_launch(void* const* d_in, const int* in_sizes, int n_in,
                              void* d_out, int out_size, void* d_ws, size_t ws_size,
                              hipStream_t stream) {
  const float* X  = (const float*)d_in[0];   // [2048,128]
  const float* Bn = (const float*)d_in[1];   // [100000,128]
  const float* W1 = (const float*)d_in[2];   // [128,64]
  const float* b1 = (const float*)d_in[3];   // [64]
  const float* W2 = (const float*)d_in[4];   // [64,1]
  const float* b2 = (const float*)d_in[5];   // [1]
  float* out = (float*)d_out;                // 2*2048*50 edge floats + 128 g floats

  char* p = (char*)d_ws;
  unsigned short* cand2 = (unsigned short*)p; p += (size_t)PN * NCP * SCAP * 2;
  unsigned char*  cnt2  = (unsigned char*)p;  p += (size_t)PN * NCP;
  float* logits = (float*)p;                  p += (size_t)PN * 4;
  short* Ap     = (short*)p;                  p += (size_t)NRB * 2048 * 8 * 2;
  short* Bp     = (short*)p;                  // NCB*128*128*2 B = 25.7 MB (zero-padded)

  k_prep<<<PB_ALL, 256, 0, stream>>>(X, Bn, W1, b1, W2, b2, Ap, Bp, logits);
  k_sim<<<512, 256, 0, stream>>>(Ap, Bp, cand2, cnt2);
  k_select<<<PN + 1, 512, 0, stream>>>(cand2, cnt2, X, Bn, logits, out);
}